// Round 7
// baseline (7414.984 us; speedup 1.0000x reference)
//
#include <hip/hip_runtime.h>
#include <hip/hip_bf16.h>
#include <hip/hip_fp16.h>
#include <stdint.h>

// Seq2Seq LSTM: B=4096, H=512, E=128, 32 enc + 32 dec steps, V_tgt=128.
// Round 7: PERSISTENT kernel (512 blocks = 2/CU co-resident, custom grid
// barrier) replacing 64 sequential launches.
//  - c-state and h_prev registerized (block owns fixed (m-tile, hcol-tile))
//  - BK=128 K-loop (8 barriers/step), 64 KB LDS, global_load_lds staging
//  - 8-slot h ring in ws; outproj fused as 4 interleaved 256-tile batches
//  - fp16 single-chain MFMA (R6-proven numerics), fp32 logits
//  - build_tables: emb-in-LDS broadcast + thread-per-g (R6: 118 us -> ~12)

#define NB     4096
#define SSRC   32
#define STGT   32
#define NVSRC  96
#define NVTGT  128
#define ED     128
#define HD     512
#define G4     2048   // 4*HD
#define NBLK   512    // persistent grid; 2 blocks/CU on 256 CUs

typedef __attribute__((ext_vector_type(8))) _Float16 half8;
typedef __attribute__((ext_vector_type(4))) float fx4;

#define AS_G __attribute__((address_space(1)))
#define AS_L __attribute__((address_space(3)))

__device__ __forceinline__ void gl2lds16(const void* g, void* l) {
    __builtin_amdgcn_global_load_lds((const AS_G uint32_t*)g, (AS_L uint32_t*)l, 16, 0, 0);
}

__device__ __forceinline__ float sigf(float x) { return 1.0f / (1.0f + __expf(-x)); }
__device__ __forceinline__ float tanhfast(float x) { return 1.0f - 2.0f / (__expf(2.0f * x) + 1.0f); }

// Grid barrier: monotonic counter, all blocks add 1, spin until 512*epoch.
// Entry __syncthreads drains each wave's stores (compiler emits vmcnt(0));
// ACQ_REL agent RMW flushes L2 (release); trailing fence invalidates (acquire).
__device__ __forceinline__ void gbar(unsigned int* cnt, unsigned int target) {
    __syncthreads();
    if (threadIdx.x == 0) {
        __hip_atomic_fetch_add(cnt, 1u, __ATOMIC_ACQ_REL, __HIP_MEMORY_SCOPE_AGENT);
        while (__hip_atomic_load(cnt, __ATOMIC_RELAXED, __HIP_MEMORY_SCOPE_AGENT) < target)
            __builtin_amdgcn_s_sleep(2);
    }
    __syncthreads();
    __threadfence();
}

__global__ void convert_half(const float* __restrict__ src, int n, _Float16* __restrict__ dst) {
    int i = blockIdx.x * 256 + threadIdx.x;
    if (i < n) dst[i] = (_Float16)src[i];
}

// proj[v][g] = emb[v,:]·Wih[g,:] + bih[g] + bhh[g].  16 blocks: 0-7 src, 8-15 tgt.
// emb staged in LDS (broadcast reads); thread owns one g, walks its W row.
__global__ __launch_bounds__(256) void build_tables2(
    const float* __restrict__ emb_s, const float* __restrict__ Wih_s,
    const float* __restrict__ bih_s, const float* __restrict__ bhh_s,
    const float* __restrict__ emb_t, const float* __restrict__ Wih_t,
    const float* __restrict__ bih_t, const float* __restrict__ bhh_t,
    float* __restrict__ proj_s, float* __restrict__ proj_t)
{
    __shared__ float embL[NVTGT * ED];   // 64 KB max
    const bool tgt = blockIdx.x >= 8;
    const float* emb = tgt ? emb_t : emb_s;
    const float* Wih = tgt ? Wih_t : Wih_s;
    const float* bih = tgt ? bih_t : bih_s;
    const float* bhh = tgt ? bhh_t : bhh_s;
    float* proj = tgt ? proj_t : proj_s;
    const int nv = tgt ? NVTGT : NVSRC;
    const int g = ((int)blockIdx.x & 7) * 256 + threadIdx.x;
    for (int i = threadIdx.x; i < nv * ED; i += 256) embL[i] = emb[i];
    __syncthreads();
    const float bb = bih[g] + bhh[g];
    const float* wrow = Wih + (size_t)g * ED;
    for (int v0 = 0; v0 < nv; v0 += 8) {
        float acc[8] = {0, 0, 0, 0, 0, 0, 0, 0};
        for (int ec = 0; ec < ED; ec += 32) {
            float4 wv[8];
            #pragma unroll
            for (int q = 0; q < 8; q++) wv[q] = *(const float4*)&wrow[ec + q * 4];
            #pragma unroll
            for (int v = 0; v < 8; v++) {
                const float* el = &embL[(v0 + v) * ED + ec];
                float s = 0.f;
                #pragma unroll
                for (int q = 0; q < 8; q++) {
                    float4 e4 = *(const float4*)&el[q * 4];
                    s += e4.x * wv[q].x + e4.y * wv[q].y + e4.z * wv[q].z + e4.w * wv[q].w;
                }
                acc[v] += s;
            }
        }
        #pragma unroll
        for (int v = 0; v < 8; v++)
            proj[(size_t)(v0 + v) * G4 + g] = acc[v] + bb;
    }
}

__global__ __launch_bounds__(256, 2) void lstm_persistent(
    _Float16* __restrict__ ring0,            // 8 slots x NB*HD fp16
    const _Float16* __restrict__ eW, const _Float16* __restrict__ dW,
    const _Float16* __restrict__ Wo,
    const float* __restrict__ proj_s, const float* __restrict__ proj_t,
    const float* __restrict__ bout,
    const int* __restrict__ src_seq, const int* __restrict__ lens,
    const int* __restrict__ tgt_seq,
    float* __restrict__ out, unsigned int* __restrict__ cnt)
{
    __shared__ __align__(16) _Float16 lsA[128 * 128];   // 32 KB
    __shared__ __align__(16) _Float16 lsB[128 * 128];   // 32 KB

    const int tid  = threadIdx.x;
    const int lane = tid & 63;
    const int wid  = tid >> 6;
    const int rl   = lane >> 4;        // staging: row-in-quad (0..3)
    const int gp   = lane & 15;        // staging: 16B-granule position
    const int wm    = (wid >> 1) * 64; // wave m-offset
    const int wncol = wid & 1;         // wave n-column (0/1)
    const int quad  = lane >> 4;
    const int l15   = lane & 15;

    // gate-GEMM tile from XCD-swizzled blockIdx (R6 mapping)
    const int x = (int)blockIdx.x & 7, j = (int)blockIdx.x >> 3;
    const int m0 = ((x & 1) * 16 + (j & 15)) * 128;    // batch tile
    const int c0 = ((x >> 1) * 4 + (j >> 4)) * 32;     // hcol tile
    const int hcol = c0 + wncol * 16 + l15;

    float creg[16], hreg[16];
    #pragma unroll
    for (int i = 0; i < 16; i++) { creg[i] = 0.f; hreg[i] = 0.f; }

    unsigned int epoch = 0;

    for (int s = 0; s < 64; s++) {
        epoch++;
        gbar(cnt, epoch * NBLK);
        const bool enc = s < 32;
        const _Float16* hsrc = ring0 + (size_t)(s & 7) * NB * HD;
        _Float16* hdst = ring0 + (size_t)((s + 1) & 7) * NB * HD;
        const _Float16* Wp = enc ? eW : dW;
        const float* proj = enc ? proj_s : proj_t;

        fx4 acc[4][4];
        #pragma unroll
        for (int a = 0; a < 4; a++)
            #pragma unroll
            for (int b = 0; b < 4; b++)
                acc[a][b] = fx4{0.f, 0.f, 0.f, 0.f};

        if (s != 0) {            // s==0: h==0 -> GEMM term is zero
            for (int k0 = 0; k0 < HD; k0 += 128) {
                __syncthreads();
                #pragma unroll
                for (int i = 0; i < 8; i++) {
                    int r  = wid * 32 + i * 4 + rl;                 // local row
                    int cg = (gp & 8) | ((gp & 7) ^ (r & 7));       // swizzled src granule
                    const _Float16* ga = hsrc + (size_t)(m0 + r) * HD + k0 + cg * 8;
                    int wr = ((r >> 4) & 3) * HD + c0 + ((r >> 6) << 4) + (r & 15);
                    const _Float16* gb = Wp + (size_t)wr * HD + k0 + cg * 8;
                    gl2lds16(ga, &lsA[(wid * 32 + i * 4) * 128]);
                    gl2lds16(gb, &lsB[(wid * 32 + i * 4) * 128]);
                }
                __syncthreads();
                #pragma unroll
                for (int kk = 0; kk < 4; kk++) {
                    const int kc = kk * 4 + quad;
                    half8 af[4], bf[4];
                    #pragma unroll
                    for (int mt = 0; mt < 4; mt++) {
                        int ar = wm + mt * 16 + l15;
                        int pc = (kc & 8) | ((kc & 7) ^ (ar & 7));
                        af[mt] = *(const half8*)&lsA[ar * 128 + pc * 8];
                    }
                    #pragma unroll
                    for (int nt = 0; nt < 4; nt++) {
                        int br = wncol * 64 + nt * 16 + l15;
                        int pc = (kc & 8) | ((kc & 7) ^ (br & 7));
                        bf[nt] = *(const half8*)&lsB[br * 128 + pc * 8];
                    }
                    #pragma unroll
                    for (int mt = 0; mt < 4; mt++)
                        #pragma unroll
                        for (int nt = 0; nt < 4; nt++)
                            acc[mt][nt] = __builtin_amdgcn_mfma_f32_16x16x32_f16(af[mt], bf[nt], acc[mt][nt], 0, 0, 0);
                }
            }
        }

        // fused cell epilogue (all 4 gates per lane)
        #pragma unroll
        for (int mt = 0; mt < 4; mt++) {
            #pragma unroll
            for (int r = 0; r < 4; r++) {
                int li = mt * 4 + r;
                int row = m0 + wm + mt * 16 + quad * 4 + r;
                int tok;
                if (enc) tok = src_seq[row * SSRC + s];
                else { int t = s - 32; tok = (t == 0) ? 1 : tgt_seq[row * STGT + t - 1]; }
                const float* xp = proj + (size_t)tok * G4 + hcol;
                float gi = acc[mt][0][r] + xp[0];
                float gf = acc[mt][1][r] + xp[HD];
                float gg = acc[mt][2][r] + xp[2 * HD];
                float go = acc[mt][3][r] + xp[3 * HD];
                float ii = sigf(gi), ff = sigf(gf), oo = sigf(go);
                float g2 = tanhfast(gg);
                float c2 = ff * creg[li] + ii * g2;
                float h2 = oo * tanhfast(c2);
                h2 = (float)(_Float16)h2;               // store-rounded
                if (enc && s >= lens[row]) { c2 = creg[li]; h2 = hreg[li]; }
                creg[li] = c2; hreg[li] = h2;
                hdst[(size_t)row * HD + hcol] = (_Float16)h2;
            }
        }

        // outproj batch every 8 decoder steps: 256 tiles (8 t x 32 row-tiles)
        if (!enc && (((s - 32) & 7) == 7)) {
            epoch++;
            gbar(cnt, epoch * NBLK);
            if ((int)blockIdx.x < 256) {
                int t = (s - 32) - 7 + ((int)blockIdx.x >> 5);
                int m0o = ((int)blockIdx.x & 31) * 128;
                const _Float16* As = ring0 + (size_t)((t + 1) & 7) * NB * HD;
                fx4 oa[4][4];
                #pragma unroll
                for (int a = 0; a < 4; a++)
                    #pragma unroll
                    for (int b = 0; b < 4; b++)
                        oa[a][b] = fx4{0.f, 0.f, 0.f, 0.f};
                for (int k0 = 0; k0 < HD; k0 += 128) {
                    __syncthreads();
                    #pragma unroll
                    for (int i = 0; i < 8; i++) {
                        int r  = wid * 32 + i * 4 + rl;
                        int cg = (gp & 8) | ((gp & 7) ^ (r & 7));
                        const _Float16* ga = As + (size_t)(m0o + r) * HD + k0 + cg * 8;
                        const _Float16* gb = Wo + (size_t)r * HD + k0 + cg * 8;  // plain rows
                        gl2lds16(ga, &lsA[(wid * 32 + i * 4) * 128]);
                        gl2lds16(gb, &lsB[(wid * 32 + i * 4) * 128]);
                    }
                    __syncthreads();
                    #pragma unroll
                    for (int kk = 0; kk < 4; kk++) {
                        const int kc = kk * 4 + quad;
                        half8 af[4], bf[4];
                        #pragma unroll
                        for (int mt = 0; mt < 4; mt++) {
                            int ar = wm + mt * 16 + l15;
                            int pc = (kc & 8) | ((kc & 7) ^ (ar & 7));
                            af[mt] = *(const half8*)&lsA[ar * 128 + pc * 8];
                        }
                        #pragma unroll
                        for (int nt = 0; nt < 4; nt++) {
                            int br = wncol * 64 + nt * 16 + l15;
                            int pc = (kc & 8) | ((kc & 7) ^ (br & 7));
                            bf[nt] = *(const half8*)&lsB[br * 128 + pc * 8];
                        }
                        #pragma unroll
                        for (int mt = 0; mt < 4; mt++)
                            #pragma unroll
                            for (int nt = 0; nt < 4; nt++)
                                oa[mt][nt] = __builtin_amdgcn_mfma_f32_16x16x32_f16(af[mt], bf[nt], oa[mt][nt], 0, 0, 0);
                    }
                }
                #pragma unroll
                for (int mt = 0; mt < 4; mt++)
                    #pragma unroll
                    for (int nt = 0; nt < 4; nt++) {
                        int v = wncol * 64 + nt * 16 + l15;
                        float bo = bout[v];
                        #pragma unroll
                        for (int r = 0; r < 4; r++) {
                            int row = m0o + wm + mt * 16 + quad * 4 + r;
                            out[((size_t)row * STGT + t) * NVTGT + v] = oa[mt][nt][r] + bo;
                        }
                    }
            }
        }
    }
}

extern "C" void kernel_launch(void* const* d_in, const int* in_sizes, int n_in,
                              void* d_out, int out_size, void* d_ws, size_t ws_size,
                              hipStream_t stream) {
    (void)in_sizes; (void)n_in; (void)out_size; (void)ws_size;
    const int* src_seq = (const int*)d_in[0];
    const int* src_len = (const int*)d_in[1];
    const int* tgt_seq = (const int*)d_in[2];
    const float* emb_src = (const float*)d_in[3];
    const float* eWih = (const float*)d_in[4];
    const float* eWhh = (const float*)d_in[5];
    const float* ebih = (const float*)d_in[6];
    const float* ebhh = (const float*)d_in[7];
    const float* emb_tgt = (const float*)d_in[8];
    const float* dWih = (const float*)d_in[9];
    const float* dWhh = (const float*)d_in[10];
    const float* dbih = (const float*)d_in[11];
    const float* dbhh = (const float*)d_in[12];
    const float* Wout = (const float*)d_in[13];
    const float* bout = (const float*)d_in[14];
    float* out = (float*)d_out;

    char* ws = (char*)d_ws;
    size_t off = 0;
    auto carve = [&](size_t bytes) { void* p = ws + off; off += (bytes + 255) & ~(size_t)255; return p; };
    unsigned int* cnt = (unsigned int*)carve(256);
    float* proj_src = (float*)carve((size_t)NVSRC * G4 * 4);
    float* proj_tgt = (float*)carve((size_t)NVTGT * G4 * 4);
    _Float16* ring0 = (_Float16*)carve((size_t)8 * NB * HD * 2);   // 32 MB
    _Float16* eW_h  = (_Float16*)carve((size_t)G4 * HD * 2);
    _Float16* dW_h  = (_Float16*)carve((size_t)G4 * HD * 2);
    _Float16* Wo_h  = (_Float16*)carve((size_t)NVTGT * HD * 2);

    hipMemsetAsync(cnt, 0, 256, stream);

    convert_half<<<dim3(G4 * HD / 256), dim3(256), 0, stream>>>(eWhh, G4 * HD, eW_h);
    convert_half<<<dim3(G4 * HD / 256), dim3(256), 0, stream>>>(dWhh, G4 * HD, dW_h);
    convert_half<<<dim3(NVTGT * HD / 256), dim3(256), 0, stream>>>(Wout, NVTGT * HD, Wo_h);
    build_tables2<<<dim3(16), dim3(256), 0, stream>>>(
        emb_src, eWih, ebih, ebhh, emb_tgt, dWih, dbih, dbhh, proj_src, proj_tgt);

    lstm_persistent<<<dim3(NBLK), dim3(256), 0, stream>>>(
        ring0, eW_h, dW_h, Wo_h, proj_src, proj_tgt, bout,
        src_seq, src_len, tgt_seq, out, cnt);
}

// Round 8
// 2127.078 us; speedup vs baseline: 3.4860x; 3.4860x over previous
//
#include <hip/hip_runtime.h>
#include <hip/hip_bf16.h>
#include <hip/hip_fp16.h>
#include <stdint.h>

// Seq2Seq LSTM: B=4096, H=512, E=128, 32 enc + 32 dec steps, V_tgt=128.
// Round 8: revert to R6 multi-launch (R7 persistent barrier = 5 ms of spin
// contention + per-barrier L2 invalidation, FETCH 1.96 GB). Keep R7's
// validated pieces: BK=128 staging+swizzle, build_tables2, s==0 GEMM skip.
//  - fp16 single-chain MFMA (R6-proven), fused cell epilogue, fp32 logits
//  - 64 KB LDS, 2 blocks/CU, XCD-swizzled tiles

#define NB     4096
#define SSRC   32
#define STGT   32
#define NVSRC  96
#define NVTGT  128
#define ED     128
#define HD     512
#define G4     2048   // 4*HD

typedef __attribute__((ext_vector_type(8))) _Float16 half8;
typedef __attribute__((ext_vector_type(4))) float fx4;

#define AS_G __attribute__((address_space(1)))
#define AS_L __attribute__((address_space(3)))

__device__ __forceinline__ void gl2lds16(const void* g, void* l) {
    // async global->LDS DMA, 16B/lane; LDS dest = wave-uniform base + lane*16
    __builtin_amdgcn_global_load_lds((const AS_G uint32_t*)g, (AS_L uint32_t*)l, 16, 0, 0);
}

__device__ __forceinline__ float sigf(float x) { return 1.0f / (1.0f + __expf(-x)); }
__device__ __forceinline__ float tanhfast(float x) { return 1.0f - 2.0f / (__expf(2.0f * x) + 1.0f); }

__global__ void convert_half(const float* __restrict__ src, int n, _Float16* __restrict__ dst) {
    int i = blockIdx.x * 256 + threadIdx.x;
    if (i < n) dst[i] = (_Float16)src[i];
}

// proj[v][g] = emb[v,:]·Wih[g,:] + bih[g] + bhh[g].  16 blocks: 0-7 src, 8-15 tgt.
// emb staged in LDS (broadcast reads); thread owns one g, walks its W row.
// [validated R7: absmax identical]
__global__ __launch_bounds__(256) void build_tables2(
    const float* __restrict__ emb_s, const float* __restrict__ Wih_s,
    const float* __restrict__ bih_s, const float* __restrict__ bhh_s,
    const float* __restrict__ emb_t, const float* __restrict__ Wih_t,
    const float* __restrict__ bih_t, const float* __restrict__ bhh_t,
    float* __restrict__ proj_s, float* __restrict__ proj_t)
{
    __shared__ float embL[NVTGT * ED];   // 64 KB max
    const bool tgt = blockIdx.x >= 8;
    const float* emb = tgt ? emb_t : emb_s;
    const float* Wih = tgt ? Wih_t : Wih_s;
    const float* bih = tgt ? bih_t : bih_s;
    const float* bhh = tgt ? bhh_t : bhh_s;
    float* proj = tgt ? proj_t : proj_s;
    const int nv = tgt ? NVTGT : NVSRC;
    const int g = ((int)blockIdx.x & 7) * 256 + threadIdx.x;
    for (int i = threadIdx.x; i < nv * ED; i += 256) embL[i] = emb[i];
    __syncthreads();
    const float bb = bih[g] + bhh[g];
    const float* wrow = Wih + (size_t)g * ED;
    for (int v0 = 0; v0 < nv; v0 += 8) {
        float acc[8] = {0, 0, 0, 0, 0, 0, 0, 0};
        for (int ec = 0; ec < ED; ec += 32) {
            float4 wv[8];
            #pragma unroll
            for (int q = 0; q < 8; q++) wv[q] = *(const float4*)&wrow[ec + q * 4];
            #pragma unroll
            for (int v = 0; v < 8; v++) {
                const float* el = &embL[(v0 + v) * ED + ec];
                float s = 0.f;
                #pragma unroll
                for (int q = 0; q < 8; q++) {
                    float4 e4 = *(const float4*)&el[q * 4];
                    s += e4.x * wv[q].x + e4.y * wv[q].y + e4.z * wv[q].z + e4.w * wv[q].w;
                }
                acc[v] += s;
            }
        }
        #pragma unroll
        for (int v = 0; v < 8; v++)
            proj[(size_t)(v0 + v) * G4 + g] = acc[v] + bb;
    }
}

// One LSTM step. Blocks [0,n_gemm): 128 rows x 32 hcols (x4 gates) of the
// gates GEMM + fused cell epilogue. Blocks [n_gemm,...): outproj of the
// PREVIOUS step's h -> fp32 logits. BK=128 K-loop (validated R7).
__global__ __launch_bounds__(256, 2) void lstm_step(
    const _Float16* __restrict__ h_r, _Float16* __restrict__ h_w,
    float* __restrict__ c_state,
    const float* __restrict__ proj,
    const int* __restrict__ seq, const int* __restrict__ lens,
    const _Float16* __restrict__ W,
    int t, int is_enc, int n_gemm, int out_t, int skip_gemm,
    const _Float16* __restrict__ Wout, const float* __restrict__ bout,
    float* __restrict__ out)
{
    __shared__ __align__(16) _Float16 lsA[128 * 128];   // 32 KB
    __shared__ __align__(16) _Float16 lsB[128 * 128];   // 32 KB

    const int tid  = threadIdx.x;
    const int lane = tid & 63;
    const int wid  = tid >> 6;
    const int rl   = lane >> 4;        // staging: row-in-quad (0..3)
    const int gp   = lane & 15;        // staging: 16B-granule position
    const int wm    = (wid >> 1) * 64; // wave m-offset
    const int wncol = wid & 1;         // wave n-column (0/1)
    const int quad  = lane >> 4;
    const int l15   = lane & 15;

    const bool is_gemm = (int)blockIdx.x < n_gemm;
    if (!is_gemm && out_t < 0) return;
    int m0, c0 = 0;
    const _Float16 *aP[8], *bP[8];

    if (is_gemm) {
        // XCD swizzle: per-XCD working set A 2 MB + B 0.5 MB < 4 MB L2
        int x = (int)blockIdx.x & 7, j = (int)blockIdx.x >> 3;
        m0 = ((x & 1) * 16 + (j & 15)) * 128;    // batch tile
        c0 = ((x >> 1) * 4 + (j >> 4)) * 32;     // hcol tile
        #pragma unroll
        for (int i = 0; i < 8; i++) {
            int r  = wid * 32 + i * 4 + rl;                 // local row 0..127
            int cg = (gp & 8) | ((gp & 7) ^ (r & 7));       // swizzled granule
            aP[i] = h_r + (size_t)(m0 + r) * HD + cg * 8;
            // local col r -> (wavecol=r>>6, gate=(r>>4)&3, tcol=r&15)
            int wr = ((r >> 4) & 3) * HD + c0 + ((r >> 6) << 4) + (r & 15);
            bP[i] = W + (size_t)wr * HD + cg * 8;
        }
    } else {
        m0 = ((int)blockIdx.x - n_gemm) * 128;
        #pragma unroll
        for (int i = 0; i < 8; i++) {
            int r  = wid * 32 + i * 4 + rl;
            int cg = (gp & 8) | ((gp & 7) ^ (r & 7));
            aP[i] = h_r + (size_t)(m0 + r) * HD + cg * 8;
            bP[i] = Wout + (size_t)r * HD + cg * 8;         // Wout row = v
        }
    }

    fx4 acc[4][4];
    #pragma unroll
    for (int i = 0; i < 4; i++)
        #pragma unroll
        for (int j = 0; j < 4; j++)
            acc[i][j] = fx4{0.f, 0.f, 0.f, 0.f};

    if (!(skip_gemm && is_gemm)) {
        for (int k0 = 0; k0 < HD; k0 += 128) {
            __syncthreads();   // protect LDS while still being read
            #pragma unroll
            for (int i = 0; i < 8; i++) {
                int lb = (wid * 32 + i * 4) * 128;          // wave-uniform base
                gl2lds16(aP[i] + k0, &lsA[lb]);
                gl2lds16(bP[i] + k0, &lsB[lb]);
            }
            __syncthreads();   // drains vmcnt before barrier
            #pragma unroll
            for (int kk = 0; kk < 4; kk++) {
                const int kc = kk * 4 + quad;               // granule 0..15
                half8 af[4], bf[4];
                #pragma unroll
                for (int mt = 0; mt < 4; mt++) {
                    int ar = wm + mt * 16 + l15;
                    int pc = (kc & 8) | ((kc & 7) ^ (ar & 7));
                    af[mt] = *(const half8*)&lsA[ar * 128 + pc * 8];
                }
                #pragma unroll
                for (int nt = 0; nt < 4; nt++) {
                    int br = wncol * 64 + nt * 16 + l15;
                    int pc = (kc & 8) | ((kc & 7) ^ (br & 7));
                    bf[nt] = *(const half8*)&lsB[br * 128 + pc * 8];
                }
                #pragma unroll
                for (int mt = 0; mt < 4; mt++)
                    #pragma unroll
                    for (int nt = 0; nt < 4; nt++)
                        acc[mt][nt] = __builtin_amdgcn_mfma_f32_16x16x32_f16(af[mt], bf[nt], acc[mt][nt], 0, 0, 0);
            }
        }
    }

    if (is_gemm) {
        // acc[mt][gate][r]: all 4 gates for (row, hcol) live in this lane
        const int hcol = c0 + wncol * 16 + l15;
        #pragma unroll
        for (int mt = 0; mt < 4; mt++) {
            #pragma unroll
            for (int r = 0; r < 4; r++) {
                int row = m0 + wm + mt * 16 + quad * 4 + r;   // batch index
                int tok = is_enc ? seq[row * SSRC + t]
                                 : (t == 0 ? 1 : seq[row * STGT + t - 1]);  // SOS=1
                const float* xp = proj + (size_t)tok * G4 + hcol;
                float gi = acc[mt][0][r] + xp[0];
                float gf = acc[mt][1][r] + xp[HD];
                float gg = acc[mt][2][r] + xp[2 * HD];
                float go = acc[mt][3][r] + xp[3 * HD];
                float ii = sigf(gi), ff = sigf(gf), oo = sigf(go);
                float g2 = tanhfast(gg);
                size_t off = (size_t)row * HD + hcol;
                float cold = c_state[off];
                float c2 = ff * cold + ii * g2;
                float h2 = oo * tanhfast(c2);
                if (is_enc && t >= lens[row]) {   // pack_padded semantics
                    c2 = cold;
                    h2 = (float)h_r[off];          // exact fp16 carry
                }
                c_state[off] = c2;
                h_w[off] = (_Float16)h2;
            }
        }
    } else {
        // logits[:, out_t, :] = h_prev @ Wout^T + bout  (fp32 output)
        #pragma unroll
        for (int mt = 0; mt < 4; mt++) {
            #pragma unroll
            for (int nt = 0; nt < 4; nt++) {
                int v = wncol * 64 + nt * 16 + l15;
                float bo = bout[v];
                #pragma unroll
                for (int r = 0; r < 4; r++) {
                    int row = m0 + wm + mt * 16 + quad * 4 + r;
                    out[((size_t)row * STGT + out_t) * NVTGT + v] = acc[mt][nt][r] + bo;
                }
            }
        }
    }
}

extern "C" void kernel_launch(void* const* d_in, const int* in_sizes, int n_in,
                              void* d_out, int out_size, void* d_ws, size_t ws_size,
                              hipStream_t stream) {
    (void)in_sizes; (void)n_in; (void)out_size; (void)ws_size;
    const int* src_seq = (const int*)d_in[0];
    const int* src_len = (const int*)d_in[1];
    const int* tgt_seq = (const int*)d_in[2];
    const float* emb_src = (const float*)d_in[3];
    const float* eWih = (const float*)d_in[4];
    const float* eWhh = (const float*)d_in[5];
    const float* ebih = (const float*)d_in[6];
    const float* ebhh = (const float*)d_in[7];
    const float* emb_tgt = (const float*)d_in[8];
    const float* dWih = (const float*)d_in[9];
    const float* dWhh = (const float*)d_in[10];
    const float* dbih = (const float*)d_in[11];
    const float* dbhh = (const float*)d_in[12];
    const float* Wout = (const float*)d_in[13];
    const float* bout = (const float*)d_in[14];
    float* out = (float*)d_out;   // reference output dtype is float32

    char* ws = (char*)d_ws;
    size_t off = 0;
    auto carve = [&](size_t bytes) { void* p = ws + off; off += (bytes + 255) & ~(size_t)255; return p; };
    float* proj_src = (float*)carve((size_t)NVSRC * G4 * 4);
    float* proj_tgt = (float*)carve((size_t)NVTGT * G4 * 4);
    float* c_state  = (float*)carve((size_t)NB * HD * 4);
    _Float16* h[2];
    for (int i = 0; i < 2; i++) h[i] = (_Float16*)carve((size_t)NB * HD * 2);
    _Float16* eW_h = (_Float16*)carve((size_t)G4 * HD * 2);
    _Float16* dW_h = (_Float16*)carve((size_t)G4 * HD * 2);
    _Float16* Wo_h = (_Float16*)carve((size_t)NVTGT * HD * 2);

    hipMemsetAsync(c_state, 0, (size_t)NB * HD * 4, stream);
    hipMemsetAsync(h[0], 0, (size_t)NB * HD * 2, stream);

    convert_half<<<dim3(G4 * HD / 256), dim3(256), 0, stream>>>(eWhh, G4 * HD, eW_h);
    convert_half<<<dim3(G4 * HD / 256), dim3(256), 0, stream>>>(dWhh, G4 * HD, dW_h);
    convert_half<<<dim3(NVTGT * HD / 256), dim3(256), 0, stream>>>(Wout, NVTGT * HD, Wo_h);
    build_tables2<<<dim3(16), dim3(256), 0, stream>>>(
        emb_src, eWih, ebih, ebhh, emb_tgt, dWih, dbih, dbhh, proj_src, proj_tgt);

    // encoder: steps s=0..31, masked update (s=0: h==0 -> skip GEMM)
    for (int s = 0; s < 32; s++) {
        lstm_step<<<dim3(512), dim3(256), 0, stream>>>(
            h[s & 1], h[(s + 1) & 1], c_state,
            proj_src, src_seq, src_len, eW_h, s, 1, 512, -1, (s == 0),
            Wo_h, bout, out);
    }
    // decoder: steps tt=0..31; 32 extra blocks project h_{tt-1} -> out[:,tt-1,:]
    for (int tt = 0; tt < 32; tt++) {
        int s = 32 + tt;
        lstm_step<<<dim3(544), dim3(256), 0, stream>>>(
            h[s & 1], h[(s + 1) & 1], c_state,
            proj_tgt, tgt_seq, nullptr, dW_h, tt, 0, 512, tt - 1, 0,
            Wo_h, bout, out);
    }
    // tail: outproj of h after decoder step 31 (parity 0)
    lstm_step<<<dim3(32), dim3(256), 0, stream>>>(
        h[0], h[1], c_state,
        proj_tgt, tgt_seq, nullptr, dW_h, 0, 0, 0, 31, 0,
        Wo_h, bout, out);
}

// Round 9
// 1980.837 us; speedup vs baseline: 3.7434x; 1.0738x over previous
//
#include <hip/hip_runtime.h>
#include <hip/hip_bf16.h>
#include <hip/hip_fp16.h>
#include <stdint.h>

// Seq2Seq LSTM: B=4096, H=512, E=128, 32 enc + 32 dec steps, V_tgt=128.
// Round 9: R6-proven BK=64 gate kernel (BK=128 regressed, m132-style);
// decoder outproj DE-fused into 4 batched 256-block launches (544-block
// launches over-committed the 512-slot 2/CU machine -> serial tail);
// tables via W-transpose + coalesced proj kernel (R8: 75 us @ 0.6% occ).
//  - fp16 single-chain MFMA, fused cell epilogue, fp32 logits (proven)
//  - 10-slot decoder h ring + 2 encoder slots; WT aliases slot 0

#define NB     4096
#define SSRC   32
#define STGT   32
#define NVSRC  96
#define NVTGT  128
#define ED     128
#define HD     512
#define G4     2048   // 4*HD
#define NBHD   ((size_t)NB * HD)

typedef __attribute__((ext_vector_type(8))) _Float16 half8;
typedef __attribute__((ext_vector_type(4))) float fx4;

#define AS_G __attribute__((address_space(1)))
#define AS_L __attribute__((address_space(3)))

__device__ __forceinline__ void gl2lds16(const void* g, void* l) {
    // async global->LDS DMA, 16B/lane; LDS dest = wave-uniform base + lane*16
    __builtin_amdgcn_global_load_lds((const AS_G uint32_t*)g, (AS_L uint32_t*)l, 16, 0, 0);
}

__device__ __forceinline__ float sigf(float x) { return 1.0f / (1.0f + __expf(-x)); }
__device__ __forceinline__ float tanhfast(float x) { return 1.0f - 2.0f / (__expf(2.0f * x) + 1.0f); }

__global__ void convert_half(const float* __restrict__ src, int n, _Float16* __restrict__ dst) {
    int i = blockIdx.x * 256 + threadIdx.x;
    if (i < n) dst[i] = (_Float16)src[i];
}

// 32x32 LDS-tiled transpose: outT[c][r] = in[r][c]; both sides coalesced.
__global__ __launch_bounds__(256) void transpose_f32(
    const float* __restrict__ in, float* __restrict__ outT, int R, int C, int rtiles)
{
    __shared__ float ls[32][33];
    const int bx = (int)blockIdx.x % rtiles;     // r-tile
    const int by = (int)blockIdx.x / rtiles;     // c-tile
    const int tx = threadIdx.x & 31, ty = threadIdx.x >> 5;   // ty 0..7
    #pragma unroll
    for (int i = 0; i < 4; i++) {
        int rr = ty + i * 8;
        ls[rr][tx] = in[(size_t)(bx * 32 + rr) * C + by * 32 + tx];
    }
    __syncthreads();
    #pragma unroll
    for (int i = 0; i < 4; i++) {
        int rr = ty + i * 8;
        outT[(size_t)(by * 32 + rr) * R + bx * 32 + tx] = ls[tx][rr];
    }
}

// proj[v][g] = emb[v,:]·Wih[g,:] + bih[g] + bhh[g], using WT[e][g] (coalesced).
// Block: 8 v-rows x 256 g-cols. grid = (nv/8) * 8.
__global__ __launch_bounds__(256) void build_tables3(
    const float* __restrict__ emb, const float* __restrict__ WT,
    const float* __restrict__ bih, const float* __restrict__ bhh,
    float* __restrict__ proj)
{
    __shared__ float embL[8][ED];
    const int gc = (int)blockIdx.x & 7;
    const int vc = (int)blockIdx.x >> 3;
    const int g  = gc * 256 + threadIdx.x;
    for (int i = threadIdx.x; i < 8 * ED; i += 256)
        embL[i >> 7][i & (ED - 1)] = emb[(size_t)(vc * 8 + (i >> 7)) * ED + (i & (ED - 1))];
    __syncthreads();
    float acc[8] = {0, 0, 0, 0, 0, 0, 0, 0};
    for (int e = 0; e < ED; e++) {
        float w = WT[(size_t)e * G4 + g];
        #pragma unroll
        for (int v = 0; v < 8; v++) acc[v] += embL[v][e] * w;
    }
    float bb = bih[g] + bhh[g];
    #pragma unroll
    for (int v = 0; v < 8; v++)
        proj[(size_t)(vc * 8 + v) * G4 + g] = acc[v] + bb;
}

// Gate GEMM (128 rows x 32 hcols x 4 gates) + fused cell epilogue.
// 512 blocks = exactly 2/CU. BK=64 (R6-proven body).
__global__ __launch_bounds__(256, 2) void lstm_step(
    const _Float16* __restrict__ h_r, _Float16* __restrict__ h_w,
    float* __restrict__ c_state,
    const float* __restrict__ proj,
    const int* __restrict__ seq, const int* __restrict__ lens,
    const _Float16* __restrict__ W,
    int t, int is_enc, int skip_gemm)
{
    __shared__ __align__(16) _Float16 lsA[128 * 64];   // 16 KB
    __shared__ __align__(16) _Float16 lsB[128 * 64];   // 16 KB

    const int tid = threadIdx.x;
    const int lane = tid & 63;
    const int wid  = tid >> 6;
    const int srow = lane >> 3;                    // staging row-in-group
    const int skc  = (((lane & 7) ^ srow)) << 3;   // XOR-swizzled k-chunk
    const int wm    = (wid >> 1) * 64;
    const int wncol = wid & 1;
    const int quad  = lane >> 4;
    const int l15   = lane & 15;
    const int bsw   = (l15 & 7);

    // XCD swizzle: per-XCD working set A 2 MB + B 0.5 MB < 4 MB L2
    int x = (int)blockIdx.x & 7, j = (int)blockIdx.x >> 3;
    const int m0 = ((x & 1) * 16 + (j & 15)) * 128;    // batch tile
    const int c0 = ((x >> 1) * 4 + (j >> 4)) * 32;     // hcol tile

    const _Float16 *ag[4], *bg[4];
    #pragma unroll
    for (int i = 0; i < 4; i++) {
        int lr = wid * 32 + i * 8 + srow;          // local row 0..127
        ag[i] = h_r + (size_t)(m0 + lr) * HD + skc;
        // local col lr -> (wavecol=lr>>6, gate=(lr>>4)&3, tcol=lr&15)
        int wr = ((lr >> 4) & 3) * HD + c0 + ((lr >> 6) << 4) + (lr & 15);
        bg[i] = W + (size_t)wr * HD + skc;
    }

    fx4 acc[4][4];
    #pragma unroll
    for (int i = 0; i < 4; i++)
        #pragma unroll
        for (int jj = 0; jj < 4; jj++)
            acc[i][jj] = fx4{0.f, 0.f, 0.f, 0.f};

    if (!skip_gemm) {
        for (int k0 = 0; k0 < HD; k0 += 64) {
            __syncthreads();
            #pragma unroll
            for (int i = 0; i < 4; i++) {
                int lb = (wid * 32 + i * 8) * 64;
                gl2lds16(ag[i] + k0, &lsA[lb]);
                gl2lds16(bg[i] + k0, &lsB[lb]);
            }
            __syncthreads();
            #pragma unroll
            for (int kk = 0; kk < 64; kk += 32) {
                const int kc = (kk >> 3) + quad;
                const int sw = ((kc ^ bsw) << 3);
                half8 af[4], bf[4];
                #pragma unroll
                for (int mt = 0; mt < 4; mt++)
                    af[mt] = *(const half8*)&lsA[(wm + mt * 16 + l15) * 64 + sw];
                #pragma unroll
                for (int nt = 0; nt < 4; nt++)
                    bf[nt] = *(const half8*)&lsB[(wncol * 64 + nt * 16 + l15) * 64 + sw];
                #pragma unroll
                for (int mt = 0; mt < 4; mt++)
                    #pragma unroll
                    for (int nt = 0; nt < 4; nt++)
                        acc[mt][nt] = __builtin_amdgcn_mfma_f32_16x16x32_f16(af[mt], bf[nt], acc[mt][nt], 0, 0, 0);
            }
        }
    }

    // fused cell epilogue (all 4 gates per lane)
    const int hcol = c0 + wncol * 16 + l15;
    #pragma unroll
    for (int mt = 0; mt < 4; mt++) {
        #pragma unroll
        for (int r = 0; r < 4; r++) {
            int row = m0 + wm + mt * 16 + quad * 4 + r;
            int tok = is_enc ? seq[row * SSRC + t]
                             : (t == 0 ? 1 : seq[row * STGT + t - 1]);  // SOS=1
            const float* xp = proj + (size_t)tok * G4 + hcol;
            float gi = acc[mt][0][r] + xp[0];
            float gf = acc[mt][1][r] + xp[HD];
            float gg = acc[mt][2][r] + xp[2 * HD];
            float go = acc[mt][3][r] + xp[3 * HD];
            float ii = sigf(gi), ff = sigf(gf), oo = sigf(go);
            float g2 = tanhfast(gg);
            size_t off = (size_t)row * HD + hcol;
            float cold = c_state[off];
            float c2 = ff * cold + ii * g2;
            float h2 = oo * tanhfast(c2);
            if (is_enc && t >= lens[row]) {   // pack_padded semantics
                c2 = cold;
                h2 = (float)h_r[off];          // exact fp16 carry
            }
            c_state[off] = c2;
            h_w[off] = (_Float16)h2;
        }
    }
}

// Batched outproj: 256 blocks = (8 t) x (32 m-tiles), each 128x128x512.
// logits[:, t0+dt, :] = h_slot(t0+dt) @ Wout^T + bout  (fp32)
__global__ __launch_bounds__(256, 2) void outproj_batch(
    const _Float16* __restrict__ h_slots, int t0,
    const _Float16* __restrict__ Wo, const float* __restrict__ bout,
    float* __restrict__ out)
{
    __shared__ __align__(16) _Float16 lsA[128 * 64];
    __shared__ __align__(16) _Float16 lsB[128 * 64];

    const int tid = threadIdx.x;
    const int lane = tid & 63;
    const int wid  = tid >> 6;
    const int srow = lane >> 3;
    const int skc  = (((lane & 7) ^ srow)) << 3;
    const int wm    = (wid >> 1) * 64;
    const int wncol = wid & 1;
    const int quad  = lane >> 4;
    const int l15   = lane & 15;
    const int bsw   = (l15 & 7);

    const int t  = t0 + ((int)blockIdx.x >> 5);
    const int m0 = ((int)blockIdx.x & 31) * 128;
    const _Float16* h_r = h_slots + (size_t)(t % 10) * NBHD;

    const _Float16 *ag[4], *bg[4];
    #pragma unroll
    for (int i = 0; i < 4; i++) {
        int lr = wid * 32 + i * 8 + srow;
        ag[i] = h_r + (size_t)(m0 + lr) * HD + skc;
        bg[i] = Wo + (size_t)lr * HD + skc;   // Wout row = v
    }

    fx4 acc[4][4];
    #pragma unroll
    for (int i = 0; i < 4; i++)
        #pragma unroll
        for (int jj = 0; jj < 4; jj++)
            acc[i][jj] = fx4{0.f, 0.f, 0.f, 0.f};

    for (int k0 = 0; k0 < HD; k0 += 64) {
        __syncthreads();
        #pragma unroll
        for (int i = 0; i < 4; i++) {
            int lb = (wid * 32 + i * 8) * 64;
            gl2lds16(ag[i] + k0, &lsA[lb]);
            gl2lds16(bg[i] + k0, &lsB[lb]);
        }
        __syncthreads();
        #pragma unroll
        for (int kk = 0; kk < 64; kk += 32) {
            const int kc = (kk >> 3) + quad;
            const int sw = ((kc ^ bsw) << 3);
            half8 af[4], bf[4];
            #pragma unroll
            for (int mt = 0; mt < 4; mt++)
                af[mt] = *(const half8*)&lsA[(wm + mt * 16 + l15) * 64 + sw];
            #pragma unroll
            for (int nt = 0; nt < 4; nt++)
                bf[nt] = *(const half8*)&lsB[(wncol * 64 + nt * 16 + l15) * 64 + sw];
            #pragma unroll
            for (int mt = 0; mt < 4; mt++)
                #pragma unroll
                for (int nt = 0; nt < 4; nt++)
                    acc[mt][nt] = __builtin_amdgcn_mfma_f32_16x16x32_f16(af[mt], bf[nt], acc[mt][nt], 0, 0, 0);
        }
    }

    #pragma unroll
    for (int mt = 0; mt < 4; mt++)
        #pragma unroll
        for (int nt = 0; nt < 4; nt++) {
            int v = wncol * 64 + nt * 16 + l15;
            float bo = bout[v];
            #pragma unroll
            for (int r = 0; r < 4; r++) {
                int row = m0 + wm + mt * 16 + quad * 4 + r;
                out[((size_t)row * STGT + t) * NVTGT + v] = acc[mt][nt][r] + bo;
            }
        }
}

extern "C" void kernel_launch(void* const* d_in, const int* in_sizes, int n_in,
                              void* d_out, int out_size, void* d_ws, size_t ws_size,
                              hipStream_t stream) {
    (void)in_sizes; (void)n_in; (void)out_size; (void)ws_size;
    const int* src_seq = (const int*)d_in[0];
    const int* src_len = (const int*)d_in[1];
    const int* tgt_seq = (const int*)d_in[2];
    const float* emb_src = (const float*)d_in[3];
    const float* eWih = (const float*)d_in[4];
    const float* eWhh = (const float*)d_in[5];
    const float* ebih = (const float*)d_in[6];
    const float* ebhh = (const float*)d_in[7];
    const float* emb_tgt = (const float*)d_in[8];
    const float* dWih = (const float*)d_in[9];
    const float* dWhh = (const float*)d_in[10];
    const float* dbih = (const float*)d_in[11];
    const float* dbhh = (const float*)d_in[12];
    const float* Wout = (const float*)d_in[13];
    const float* bout = (const float*)d_in[14];
    float* out = (float*)d_out;

    char* ws = (char*)d_ws;
    size_t off = 0;
    auto carve = [&](size_t bytes) { void* p = ws + off; off += (bytes + 255) & ~(size_t)255; return p; };
    float* proj_src = (float*)carve((size_t)NVSRC * G4 * 4);
    float* proj_tgt = (float*)carve((size_t)NVTGT * G4 * 4);
    float* c_state  = (float*)carve(NBHD * 4);
    _Float16* slots = (_Float16*)carve((size_t)12 * NBHD * 2);   // 48 MB
    _Float16* eW_h  = (_Float16*)carve((size_t)G4 * HD * 2);
    _Float16* dW_h  = (_Float16*)carve((size_t)G4 * HD * 2);
    _Float16* Wo_h  = (_Float16*)carve((size_t)NVTGT * HD * 2);
    // WT buffers alias decoder slot 0 (first written at decoder step 0,
    // long after tables are built). 1 MB each, slot is 4 MB.
    float* WT_e = (float*)(slots);
    float* WT_d = (float*)((char*)slots + (size_t)ED * G4 * 4);
    auto slot = [&](int i) { return slots + (size_t)i * NBHD; };

    hipMemsetAsync(c_state, 0, NBHD * 4, stream);
    hipMemsetAsync(slot(10), 0, NBHD * 2, stream);   // initial h = 0

    convert_half<<<dim3(G4 * HD / 256), dim3(256), 0, stream>>>(eWhh, G4 * HD, eW_h);
    convert_half<<<dim3(G4 * HD / 256), dim3(256), 0, stream>>>(dWhh, G4 * HD, dW_h);
    convert_half<<<dim3(NVTGT * HD / 256), dim3(256), 0, stream>>>(Wout, NVTGT * HD, Wo_h);
    transpose_f32<<<dim3((G4 / 32) * (ED / 32)), dim3(256), 0, stream>>>(eWih, WT_e, G4, ED, G4 / 32);
    transpose_f32<<<dim3((G4 / 32) * (ED / 32)), dim3(256), 0, stream>>>(dWih, WT_d, G4, ED, G4 / 32);
    build_tables3<<<dim3((NVSRC / 8) * 8), dim3(256), 0, stream>>>(emb_src, WT_e, ebih, ebhh, proj_src);
    build_tables3<<<dim3((NVTGT / 8) * 8), dim3(256), 0, stream>>>(emb_tgt, WT_d, dbih, dbhh, proj_tgt);

    // encoder: slots 10/11 alternate; s=0 skips GEMM (h==0)
    for (int s = 0; s < 32; s++) {
        lstm_step<<<dim3(512), dim3(256), 0, stream>>>(
            slot(10 + (s & 1)), slot(10 + ((s + 1) & 1)), c_state,
            proj_src, src_seq, src_len, eW_h, s, 1, (s == 0));
    }
    // decoder: 10-slot ring (slot = t mod 10); outproj batches of 8
    for (int t = 0; t < 32; t++) {
        const _Float16* hr = (t == 0) ? slot(10) : slot((t - 1) % 10);
        lstm_step<<<dim3(512), dim3(256), 0, stream>>>(
            hr, slot(t % 10), c_state,
            proj_tgt, tgt_seq, nullptr, dW_h, t, 0, 0);
        if ((t & 7) == 7) {
            outproj_batch<<<dim3(256), dim3(256), 0, stream>>>(
                slots, t - 7, Wo_h, bout, out);
        }
    }
}

// Round 10
// 1574.651 us; speedup vs baseline: 4.7090x; 1.2580x over previous
//
#include <hip/hip_runtime.h>
#include <hip/hip_bf16.h>
#include <hip/hip_fp16.h>
#include <stdint.h>

// Seq2Seq LSTM: B=4096, H=512, E=128, 32 enc + 32 dec steps, V_tgt=128.
// Round 10: OCCUPANCY. R9 model: 2 blocks/CU (8 waves/CU) leaves the step
// stall-bound (~26 us vs ~6 us pipe floor). Re-tile gates GEMM to 128x64
// blocks (64n = 4 gates x 16 hcols, gate-per-n-frag epilogue preserved):
// 1024 blocks = 4/CU, 24 KB LDS, launch_bounds(256,4). Same instruction
// stream per output cell -> absmax bitwise identical.
//  - fp16 single-chain MFMA, fused cell epilogue, fp32 logits (proven)
//  - tables via transpose+coalesced kernel (R9), outproj batched (R9)

#define NB     4096
#define SSRC   32
#define STGT   32
#define NVSRC  96
#define NVTGT  128
#define ED     128
#define HD     512
#define G4     2048   // 4*HD
#define NBHD   ((size_t)NB * HD)

typedef __attribute__((ext_vector_type(8))) _Float16 half8;
typedef __attribute__((ext_vector_type(4))) float fx4;

#define AS_G __attribute__((address_space(1)))
#define AS_L __attribute__((address_space(3)))

__device__ __forceinline__ void gl2lds16(const void* g, void* l) {
    // async global->LDS DMA, 16B/lane; LDS dest = wave-uniform base + lane*16
    __builtin_amdgcn_global_load_lds((const AS_G uint32_t*)g, (AS_L uint32_t*)l, 16, 0, 0);
}

__device__ __forceinline__ float sigf(float x) { return 1.0f / (1.0f + __expf(-x)); }
__device__ __forceinline__ float tanhfast(float x) { return 1.0f - 2.0f / (__expf(2.0f * x) + 1.0f); }

__global__ void convert_half(const float* __restrict__ src, int n, _Float16* __restrict__ dst) {
    int i = blockIdx.x * 256 + threadIdx.x;
    if (i < n) dst[i] = (_Float16)src[i];
}

// 32x32 LDS-tiled transpose: outT[c][r] = in[r][c]; both sides coalesced.
__global__ __launch_bounds__(256) void transpose_f32(
    const float* __restrict__ in, float* __restrict__ outT, int R, int C, int rtiles)
{
    __shared__ float ls[32][33];
    const int bx = (int)blockIdx.x % rtiles;     // r-tile
    const int by = (int)blockIdx.x / rtiles;     // c-tile
    const int tx = threadIdx.x & 31, ty = threadIdx.x >> 5;   // ty 0..7
    #pragma unroll
    for (int i = 0; i < 4; i++) {
        int rr = ty + i * 8;
        ls[rr][tx] = in[(size_t)(bx * 32 + rr) * C + by * 32 + tx];
    }
    __syncthreads();
    #pragma unroll
    for (int i = 0; i < 4; i++) {
        int rr = ty + i * 8;
        outT[(size_t)(by * 32 + rr) * R + bx * 32 + tx] = ls[tx][rr];
    }
}

// proj[v][g] = emb[v,:]·Wih[g,:] + bih[g] + bhh[g], using WT[e][g] (coalesced).
__global__ __launch_bounds__(256) void build_tables3(
    const float* __restrict__ emb, const float* __restrict__ WT,
    const float* __restrict__ bih, const float* __restrict__ bhh,
    float* __restrict__ proj)
{
    __shared__ float embL[8][ED];
    const int gc = (int)blockIdx.x & 7;
    const int vc = (int)blockIdx.x >> 3;
    const int g  = gc * 256 + threadIdx.x;
    for (int i = threadIdx.x; i < 8 * ED; i += 256)
        embL[i >> 7][i & (ED - 1)] = emb[(size_t)(vc * 8 + (i >> 7)) * ED + (i & (ED - 1))];
    __syncthreads();
    float acc[8] = {0, 0, 0, 0, 0, 0, 0, 0};
    for (int e = 0; e < ED; e++) {
        float w = WT[(size_t)e * G4 + g];
        #pragma unroll
        for (int v = 0; v < 8; v++) acc[v] += embL[v][e] * w;
    }
    float bb = bih[g] + bhh[g];
    #pragma unroll
    for (int v = 0; v < 8; v++)
        proj[(size_t)(vc * 8 + v) * G4 + g] = acc[v] + bb;
}

// Gate GEMM, 128m x 64n (4 gates x 16 hcols) per block + fused cell epilogue.
// 1024 blocks = 4 blocks/CU (16 waves/CU). Wave = 32m x 64n: 2 m-frags x
// 4 n-frags (n-frag == gate), so each lane owns all 4 gates per (row,hcol).
__global__ __launch_bounds__(256, 4) void lstm_step(
    const _Float16* __restrict__ h_r, _Float16* __restrict__ h_w,
    float* __restrict__ c_state,
    const float* __restrict__ proj,
    const int* __restrict__ seq, const int* __restrict__ lens,
    const _Float16* __restrict__ W,
    int t, int is_enc, int skip_gemm)
{
    __shared__ __align__(16) _Float16 lsA[128 * 64];   // 16 KB
    __shared__ __align__(16) _Float16 lsB[64 * 64];    // 8 KB

    const int tid = threadIdx.x;
    const int lane = tid & 63;
    const int wid  = tid >> 6;
    const int srow = lane >> 3;                    // staging row-in-group
    const int skc  = (((lane & 7) ^ srow)) << 3;   // XOR-swizzled k-chunk
    const int wm   = wid * 32;                     // wave m-offset (0..96)
    const int quad = lane >> 4;
    const int l15  = lane & 15;

    // XCD swizzle: per-XCD ws = 16 m-tiles (2 MB A) + 8 hcol-tiles (0.5 MB B)
    const int x = (int)blockIdx.x & 7, j = (int)blockIdx.x >> 3;
    const int m0 = ((x & 1) * 16 + (j & 15)) * 128;    // batch tile (32 total)
    const int c0 = ((x >> 1) * 8 + (j >> 4)) * 16;     // hcol tile (32 total)

    const _Float16 *ag[4], *bg[2];
    #pragma unroll
    for (int i = 0; i < 4; i++) {
        int lr = wid * 32 + i * 8 + srow;              // local A row 0..127
        ag[i] = h_r + (size_t)(m0 + lr) * HD + skc;
    }
    #pragma unroll
    for (int i = 0; i < 2; i++) {
        int lr = wid * 16 + i * 8 + srow;              // local B row 0..63
        // lr -> (gate = lr>>4, tcol = lr&15)
        int wr = (lr >> 4) * HD + c0 + (lr & 15);
        bg[i] = W + (size_t)wr * HD + skc;
    }

    fx4 acc[2][4];
    #pragma unroll
    for (int i = 0; i < 2; i++)
        #pragma unroll
        for (int jj = 0; jj < 4; jj++)
            acc[i][jj] = fx4{0.f, 0.f, 0.f, 0.f};

    if (!skip_gemm) {
        for (int k0 = 0; k0 < HD; k0 += 64) {
            __syncthreads();
            #pragma unroll
            for (int i = 0; i < 4; i++)
                gl2lds16(ag[i] + k0, &lsA[(wid * 32 + i * 8) * 64]);
            #pragma unroll
            for (int i = 0; i < 2; i++)
                gl2lds16(bg[i] + k0, &lsB[(wid * 16 + i * 8) * 64]);
            __syncthreads();
            #pragma unroll
            for (int kk = 0; kk < 64; kk += 32) {
                const int kc = (kk >> 3) + quad;
                half8 af[2], bf[4];
                #pragma unroll
                for (int mf = 0; mf < 2; mf++) {
                    int ar = wm + mf * 16 + l15;
                    int sw = ((kc ^ (ar & 7)) << 3);
                    af[mf] = *(const half8*)&lsA[ar * 64 + sw];
                }
                #pragma unroll
                for (int g = 0; g < 4; g++) {
                    int br = g * 16 + l15;
                    int sw = ((kc ^ (br & 7)) << 3);
                    bf[g] = *(const half8*)&lsB[br * 64 + sw];
                }
                #pragma unroll
                for (int mf = 0; mf < 2; mf++)
                    #pragma unroll
                    for (int g = 0; g < 4; g++)
                        acc[mf][g] = __builtin_amdgcn_mfma_f32_16x16x32_f16(af[mf], bf[g], acc[mf][g], 0, 0, 0);
            }
        }
    }

    // fused cell epilogue: acc[mf][gate][r] — all 4 gates per (row,hcol)
    const int hcol = c0 + l15;
    #pragma unroll
    for (int mf = 0; mf < 2; mf++) {
        #pragma unroll
        for (int r = 0; r < 4; r++) {
            int row = m0 + wm + mf * 16 + quad * 4 + r;
            int tok = is_enc ? seq[row * SSRC + t]
                             : (t == 0 ? 1 : seq[row * STGT + t - 1]);  // SOS=1
            const float* xp = proj + (size_t)tok * G4 + hcol;
            float gi = acc[mf][0][r] + xp[0];
            float gf = acc[mf][1][r] + xp[HD];
            float gg = acc[mf][2][r] + xp[2 * HD];
            float go = acc[mf][3][r] + xp[3 * HD];
            float ii = sigf(gi), ff = sigf(gf), oo = sigf(go);
            float g2 = tanhfast(gg);
            size_t off = (size_t)row * HD + hcol;
            float cold = c_state[off];
            float c2 = ff * cold + ii * g2;
            float h2 = oo * tanhfast(c2);
            if (is_enc && t >= lens[row]) {   // pack_padded semantics
                c2 = cold;
                h2 = (float)h_r[off];          // exact fp16 carry
            }
            c_state[off] = c2;
            h_w[off] = (_Float16)h2;
        }
    }
}

// Batched outproj: 256 blocks = (8 t) x (32 m-tiles), each 128x128x512.
__global__ __launch_bounds__(256, 2) void outproj_batch(
    const _Float16* __restrict__ h_slots, int t0,
    const _Float16* __restrict__ Wo, const float* __restrict__ bout,
    float* __restrict__ out)
{
    __shared__ __align__(16) _Float16 lsA[128 * 64];
    __shared__ __align__(16) _Float16 lsB[128 * 64];

    const int tid = threadIdx.x;
    const int lane = tid & 63;
    const int wid  = tid >> 6;
    const int srow = lane >> 3;
    const int skc  = (((lane & 7) ^ srow)) << 3;
    const int wm    = (wid >> 1) * 64;
    const int wncol = wid & 1;
    const int quad  = lane >> 4;
    const int l15   = lane & 15;
    const int bsw   = (l15 & 7);

    const int t  = t0 + ((int)blockIdx.x >> 5);
    const int m0 = ((int)blockIdx.x & 31) * 128;
    const _Float16* h_r = h_slots + (size_t)(t % 10) * NBHD;

    const _Float16 *ag[4], *bg[4];
    #pragma unroll
    for (int i = 0; i < 4; i++) {
        int lr = wid * 32 + i * 8 + srow;
        ag[i] = h_r + (size_t)(m0 + lr) * HD + skc;
        bg[i] = Wo + (size_t)lr * HD + skc;   // Wout row = v
    }

    fx4 acc[4][4];
    #pragma unroll
    for (int i = 0; i < 4; i++)
        #pragma unroll
        for (int jj = 0; jj < 4; jj++)
            acc[i][jj] = fx4{0.f, 0.f, 0.f, 0.f};

    for (int k0 = 0; k0 < HD; k0 += 64) {
        __syncthreads();
        #pragma unroll
        for (int i = 0; i < 4; i++) {
            int lb = (wid * 32 + i * 8) * 64;
            gl2lds16(ag[i] + k0, &lsA[lb]);
            gl2lds16(bg[i] + k0, &lsB[lb]);
        }
        __syncthreads();
        #pragma unroll
        for (int kk = 0; kk < 64; kk += 32) {
            const int kc = (kk >> 3) + quad;
            const int sw = ((kc ^ bsw) << 3);
            half8 af[4], bf[4];
            #pragma unroll
            for (int mt = 0; mt < 4; mt++)
                af[mt] = *(const half8*)&lsA[(wm + mt * 16 + l15) * 64 + sw];
            #pragma unroll
            for (int nt = 0; nt < 4; nt++)
                bf[nt] = *(const half8*)&lsB[(wncol * 64 + nt * 16 + l15) * 64 + sw];
            #pragma unroll
            for (int mt = 0; mt < 4; mt++)
                #pragma unroll
                for (int nt = 0; nt < 4; nt++)
                    acc[mt][nt] = __builtin_amdgcn_mfma_f32_16x16x32_f16(af[mt], bf[nt], acc[mt][nt], 0, 0, 0);
        }
    }

    #pragma unroll
    for (int mt = 0; mt < 4; mt++)
        #pragma unroll
        for (int nt = 0; nt < 4; nt++) {
            int v = wncol * 64 + nt * 16 + l15;
            float bo = bout[v];
            #pragma unroll
            for (int r = 0; r < 4; r++) {
                int row = m0 + wm + mt * 16 + quad * 4 + r;
                out[((size_t)row * STGT + t) * NVTGT + v] = acc[mt][nt][r] + bo;
            }
        }
}

extern "C" void kernel_launch(void* const* d_in, const int* in_sizes, int n_in,
                              void* d_out, int out_size, void* d_ws, size_t ws_size,
                              hipStream_t stream) {
    (void)in_sizes; (void)n_in; (void)out_size; (void)ws_size;
    const int* src_seq = (const int*)d_in[0];
    const int* src_len = (const int*)d_in[1];
    const int* tgt_seq = (const int*)d_in[2];
    const float* emb_src = (const float*)d_in[3];
    const float* eWih = (const float*)d_in[4];
    const float* eWhh = (const float*)d_in[5];
    const float* ebih = (const float*)d_in[6];
    const float* ebhh = (const float*)d_in[7];
    const float* emb_tgt = (const float*)d_in[8];
    const float* dWih = (const float*)d_in[9];
    const float* dWhh = (const float*)d_in[10];
    const float* dbih = (const float*)d_in[11];
    const float* dbhh = (const float*)d_in[12];
    const float* Wout = (const float*)d_in[13];
    const float* bout = (const float*)d_in[14];
    float* out = (float*)d_out;

    char* ws = (char*)d_ws;
    size_t off = 0;
    auto carve = [&](size_t bytes) { void* p = ws + off; off += (bytes + 255) & ~(size_t)255; return p; };
    float* proj_src = (float*)carve((size_t)NVSRC * G4 * 4);
    float* proj_tgt = (float*)carve((size_t)NVTGT * G4 * 4);
    float* c_state  = (float*)carve(NBHD * 4);
    _Float16* slots = (_Float16*)carve((size_t)12 * NBHD * 2);   // 48 MB
    _Float16* eW_h  = (_Float16*)carve((size_t)G4 * HD * 2);
    _Float16* dW_h  = (_Float16*)carve((size_t)G4 * HD * 2);
    _Float16* Wo_h  = (_Float16*)carve((size_t)NVTGT * HD * 2);
    // WT buffers alias decoder slot 0 (first written at decoder step 0,
    // long after tables are built). 1 MB each, slot is 4 MB.
    float* WT_e = (float*)(slots);
    float* WT_d = (float*)((char*)slots + (size_t)ED * G4 * 4);
    auto slot = [&](int i) { return slots + (size_t)i * NBHD; };

    hipMemsetAsync(c_state, 0, NBHD * 4, stream);
    hipMemsetAsync(slot(10), 0, NBHD * 2, stream);   // initial h = 0

    convert_half<<<dim3(G4 * HD / 256), dim3(256), 0, stream>>>(eWhh, G4 * HD, eW_h);
    convert_half<<<dim3(G4 * HD / 256), dim3(256), 0, stream>>>(dWhh, G4 * HD, dW_h);
    convert_half<<<dim3(NVTGT * HD / 256), dim3(256), 0, stream>>>(Wout, NVTGT * HD, Wo_h);
    transpose_f32<<<dim3((G4 / 32) * (ED / 32)), dim3(256), 0, stream>>>(eWih, WT_e, G4, ED, G4 / 32);
    transpose_f32<<<dim3((G4 / 32) * (ED / 32)), dim3(256), 0, stream>>>(dWih, WT_d, G4, ED, G4 / 32);
    build_tables3<<<dim3((NVSRC / 8) * 8), dim3(256), 0, stream>>>(emb_src, WT_e, ebih, ebhh, proj_src);
    build_tables3<<<dim3((NVTGT / 8) * 8), dim3(256), 0, stream>>>(emb_tgt, WT_d, dbih, dbhh, proj_tgt);

    // encoder: slots 10/11 alternate; s=0 skips GEMM (h==0)
    for (int s = 0; s < 32; s++) {
        lstm_step<<<dim3(1024), dim3(256), 0, stream>>>(
            slot(10 + (s & 1)), slot(10 + ((s + 1) & 1)), c_state,
            proj_src, src_seq, src_len, eW_h, s, 1, (s == 0));
    }
    // decoder: 10-slot ring (slot = t mod 10); outproj batches of 8
    for (int t = 0; t < 32; t++) {
        const _Float16* hr = (t == 0) ? slot(10) : slot((t - 1) % 10);
        lstm_step<<<dim3(1024), dim3(256), 0, stream>>>(
            hr, slot(t % 10), c_state,
            proj_tgt, tgt_seq, nullptr, dW_h, t, 0, 0);
        if ((t & 7) == 7) {
            outproj_batch<<<dim3(256), dim3(256), 0, stream>>>(
                slots, t - 7, Wo_h, bout, out);
        }
    }
}